// Round 1
// baseline (860.493 us; speedup 1.0000x reference)
//
#include <hip/hip_runtime.h>
#include <cfloat>
#include <cmath>

#define NB 2048      // nodes
#define BB 16        // batch
#define DD 128       // feature dim
#define HH 64        // hidden dim
#define MAXC 5
#define CSMAX 3
#define THREADS 256

// ---------------- Threefry-2x32 (JAX-exact) ----------------
__device__ __forceinline__ unsigned rotl32(unsigned v, int d) {
  return (v << d) | (v >> (32 - d));
}

__device__ __forceinline__ void tf2x32(unsigned k0, unsigned k1, unsigned x0, unsigned x1,
                                       unsigned& o0, unsigned& o1) {
  unsigned ks2 = k0 ^ k1 ^ 0x1BD11BDAu;
  x0 += k0; x1 += k1;
#define RND(r) { x0 += x1; x1 = rotl32(x1, r); x1 ^= x0; }
  RND(13) RND(15) RND(26) RND(6)   x0 += k1;  x1 += ks2 + 1u;
  RND(17) RND(29) RND(16) RND(24)  x0 += ks2; x1 += k0 + 2u;
  RND(13) RND(15) RND(26) RND(6)   x0 += k0;  x1 += k1 + 3u;
  RND(17) RND(29) RND(16) RND(24)  x0 += k1;  x1 += ks2 + 4u;
  RND(13) RND(15) RND(26) RND(6)   x0 += ks2; x1 += k0 + 5u;
#undef RND
  o0 = x0; o1 = x1;
}

// Gumbel noise for flat element idx under key (k0,k1):
// partitionable random_bits: counts = uint64 iota -> (hi,lo)=(0,idx); bits = o0^o1
__device__ __forceinline__ float gumbel_for(unsigned k0, unsigned k1, unsigned idx) {
  unsigned o0, o1;
  tf2x32(k0, k1, 0u, idx, o0, o1);
  unsigned bits = o0 ^ o1;
  float u = __uint_as_float((bits >> 9) | 0x3f800000u) - 1.0f;
  float uu = u + 1e-8f;
  return -logf(-logf(uu) + 1e-8f);
}

// ---------------- Precompute P = x @ W1[:, :DD]^T  ([B*N, HH]) ----------------
__global__ __launch_bounds__(THREADS) void gvp_precompute(
    const float* __restrict__ x, const float* __restrict__ W1, float* __restrict__ P) {
  int gid = blockIdx.x * THREADS + threadIdx.x;  // B*N*HH total
  int j = gid & (HH - 1);
  int node = gid >> 6;
  if (node >= BB * NB) return;
  const float4* xr = (const float4*)(x + (size_t)node * DD);
  const float4* wr = (const float4*)(W1 + (size_t)j * (DD + HH));
  float acc = 0.f;
#pragma unroll
  for (int q = 0; q < DD / 4; q++) {
    float4 a = xr[q], w = wr[q];
    acc += a.x * w.x + a.y * w.y + a.z * w.z + a.w * w.w;
  }
  P[(size_t)node * HH + j] = acc;
}

// ---------------- Main sequential kernel: one block per batch ----------------
__global__ __launch_bounds__(THREADS) void gvp_main(
    const float* __restrict__ x, const float* __restrict__ adj, const int* __restrict__ mask,
    const float* __restrict__ W1, const float* __restrict__ b1,
    const float* __restrict__ W2, const float* __restrict__ b2,
    const float* __restrict__ Wc, const float* __restrict__ bc,
    const float* __restrict__ Wih, const float* __restrict__ Whh,
    const float* __restrict__ bih, const float* __restrict__ bhh,
    const float* __restrict__ P,
    float* __restrict__ out_feat, float* __restrict__ out_adjm, float* __restrict__ out_assign) {
  const int b = blockIdx.x;
  const int tid = threadIdx.x;

  __shared__ float s_logits[NB];
  __shared__ unsigned char s_avail[NB], s_reach[NB], s_nb[NB], s_cur[NB];
  __shared__ short s_list[NB];
  __shared__ int s_cnt;
  __shared__ float s_ctx[HH], s_q[HH], s_h[HH];
  __shared__ float s_hist[MAXC][DD];
  __shared__ float s_gi[3 * HH], s_gh[3 * HH];
  __shared__ float s_redv[THREADS];
  __shared__ int s_redi[THREADS];
  __shared__ int s_mem[CSMAX];
  __shared__ int s_memCnt;
  __shared__ float s_part[2][DD];

  const size_t xb = (size_t)b * NB * DD;
  const size_t adjb = (size_t)b * NB * NB;

  // ---- mean over nodes + avail init ----
  {
    int half = tid >> 7, d = tid & (DD - 1);
    float acc = 0.f;
    for (int n = half; n < NB; n += 2) acc += x[xb + (size_t)n * DD + d];
    s_part[half][d] = acc;
  }
  for (int n = tid; n < NB; n += THREADS) s_avail[n] = (mask[b * NB + n] != 0) ? 1 : 0;
  __syncthreads();
  if (tid < DD) s_part[0][tid] = (s_part[0][tid] + s_part[1][tid]) / (float)NB;
  __syncthreads();
  if (tid < HH) {
    float acc = bc[tid];
    const float* wr = Wc + (size_t)tid * DD;
    for (int d = 0; d < DD; d++) acc += s_part[0][d] * wr[d];
    s_ctx[tid] = acc;
    s_h[tid] = 0.f;
  }
  __syncthreads();

  for (int c = 0; c < MAXC; c++) {
    // q = b1 + W1[:, DD:] @ ctx
    if (tid < HH) {
      float acc = b1[tid];
      const float* wr = W1 + (size_t)tid * (DD + HH) + DD;
      for (int k = 0; k < HH; k++) acc += wr[k] * s_ctx[k];
      s_q[tid] = acc;
    }
    if (tid == 0) s_memCnt = 0;
    __syncthreads();

    // logits[n] = b2 + sum_j W2[j] * relu(P[n,j] + q[j])
    {
      float bias = b2[0];
      for (int n = tid; n < NB; n += THREADS) {
        const float* pr = P + (size_t)(b * NB + n) * HH;
        float acc = bias;
#pragma unroll 8
        for (int j = 0; j < HH; j++) {
          float h = pr[j] + s_q[j];
          acc += W2[j] * (h > 0.f ? h : 0.f);
        }
        s_logits[n] = acc;
      }
    }
    __syncthreads();

    for (int s = 0; s < CSMAX; s++) {
      unsigned data = (s == 0) ? (unsigned)(2 * c) : (unsigned)(2 * c + 1000 + (s - 1));
      unsigned k0, k1;
      tf2x32(0u, 42u, 0u, data, k0, k1);  // fold_in(key(42), data)

      float bestv = -FLT_MAX;
      int besti = NB;
      for (int n = tid; n < NB; n += THREADS) {
        bool cand = s_avail[n] && (s == 0 || s_reach[n]);
        if (cand) {
          float g = gumbel_for(k0, k1, (unsigned)(b * NB + n));
          float y = s_logits[n] + g;
          if (y > bestv) { bestv = y; besti = n; }
        }
      }
      s_redv[tid] = bestv;
      s_redi[tid] = besti;
      __syncthreads();
      for (int off = THREADS / 2; off > 0; off >>= 1) {
        if (tid < off) {
          float v2 = s_redv[tid + off];
          int i2 = s_redi[tid + off];
          if (v2 > s_redv[tid] || (v2 == s_redv[tid] && i2 < s_redi[tid])) {
            s_redv[tid] = v2; s_redi[tid] = i2;
          }
        }
        __syncthreads();
      }
      int selIdx = (s_redv[0] > -FLT_MAX) ? s_redi[0] : -1;  // -1: no candidates -> zero row
      if (tid == 0 && selIdx >= 0) {
        s_avail[selIdx] = 0;
        s_mem[s_memCnt++] = selIdx;
      }
      __syncthreads();

      if (s == 0) {
        // k-hop BFS from seed (reach starts = seed)
        for (int n = tid; n < NB; n += THREADS) {
          unsigned char v = (selIdx >= 0 && n == selIdx) ? 1 : 0;
          s_reach[n] = v; s_cur[n] = v;
        }
        __syncthreads();
        for (int hop = 0; hop < 2; hop++) {
          if (tid == 0) s_cnt = 0;
          for (int n = tid; n < NB; n += THREADS) s_nb[n] = 0;
          __syncthreads();
          for (int n = tid; n < NB; n += THREADS)
            if (s_cur[n]) { int p = atomicAdd(&s_cnt, 1); s_list[p] = (short)n; }
          __syncthreads();
          int cnt = s_cnt;
          for (int w = tid; w < cnt * NB; w += THREADS) {
            int li = w >> 11;
            int m = w & (NB - 1);
            int n = s_list[li];
            if (adj[adjb + (size_t)n * NB + m] > 0.f) s_nb[m] = 1;
          }
          __syncthreads();
          for (int m = tid; m < NB; m += THREADS) {
            unsigned char nbv = s_nb[m];
            unsigned char nw = (nbv && !s_reach[m]) ? 1 : 0;
            if (nbv) s_reach[m] = 1;
            s_cur[m] = nw;
          }
          __syncthreads();
        }
      }
    }  // selections

    // assign[:, :, c]
    {
      int m0 = s_memCnt > 0 ? s_mem[0] : -1;
      int m1 = s_memCnt > 1 ? s_mem[1] : -1;
      int m2 = s_memCnt > 2 ? s_mem[2] : -1;
      for (int n = tid; n < NB; n += THREADS) {
        float v = (n == m0 || n == m1 || n == m2) ? 1.0f : 0.0f;
        out_assign[(size_t)(b * NB + n) * MAXC + c] = v;
      }
    }
    // embedding = mean of member rows
    if (tid < DD) {
      float acc = 0.f;
      for (int i = 0; i < s_memCnt; i++) acc += x[xb + (size_t)s_mem[i] * DD + tid];
      float denom = (s_memCnt > 0) ? (float)s_memCnt : 1.0f;
      float e = acc / denom;
      s_hist[c][tid] = e;
      out_feat[((size_t)b * MAXC + c) * DD + tid] = e;
    }
    __syncthreads();

    // GRU over full history 0..c, h0 = previous h
    for (int t = 0; t <= c; t++) {
      if (tid < 3 * HH) {
        const float* wi = Wih + (size_t)tid * DD;
        float gi = bih[tid];
        for (int d = 0; d < DD; d++) gi += wi[d] * s_hist[t][d];
        const float* wh = Whh + (size_t)tid * HH;
        float gh = bhh[tid];
        for (int j = 0; j < HH; j++) gh += wh[j] * s_h[j];
        s_gi[tid] = gi;
        s_gh[tid] = gh;
      }
      __syncthreads();
      if (tid < HH) {
        float r = 1.f / (1.f + expf(-(s_gi[tid] + s_gh[tid])));
        float z = 1.f / (1.f + expf(-(s_gi[HH + tid] + s_gh[HH + tid])));
        float nn = tanhf(s_gi[2 * HH + tid] + r * s_gh[2 * HH + tid]);
        s_h[tid] = (1.f - z) * nn + z * s_h[tid];
      }
      __syncthreads();
    }
    if (tid < HH) s_ctx[tid] = s_h[tid];
    __syncthreads();
  }  // clusters

  // cluster_adj = ones - eye
  for (int i = tid; i < MAXC * MAXC; i += THREADS)
    out_adjm[(size_t)b * MAXC * MAXC + i] = ((i / MAXC) == (i % MAXC)) ? 0.f : 1.f;
}

extern "C" void kernel_launch(void* const* d_in, const int* in_sizes, int n_in,
                              void* d_out, int out_size, void* d_ws, size_t ws_size,
                              hipStream_t stream) {
  const float* x   = (const float*)d_in[0];
  const float* adj = (const float*)d_in[1];
  const int*   mask= (const int*)d_in[2];
  const float* W1  = (const float*)d_in[3];
  const float* b1  = (const float*)d_in[4];
  const float* W2  = (const float*)d_in[5];
  const float* b2  = (const float*)d_in[6];
  const float* Wc  = (const float*)d_in[7];
  const float* bc  = (const float*)d_in[8];
  const float* Wih = (const float*)d_in[9];
  const float* Whh = (const float*)d_in[10];
  const float* bih = (const float*)d_in[11];
  const float* bhh = (const float*)d_in[12];

  float* P = (float*)d_ws;  // [B*N, HH] = 8 MB
  float* out = (float*)d_out;
  float* out_feat = out;                              // [B,5,D]
  float* out_adjm = out + (size_t)BB * MAXC * DD;     // [B,5,5]
  float* out_assign = out_adjm + (size_t)BB * MAXC * MAXC;  // [B,N,5]

  hipLaunchKernelGGL(gvp_precompute, dim3((BB * NB * HH) / THREADS), dim3(THREADS), 0, stream,
                     x, W1, P);
  hipLaunchKernelGGL(gvp_main, dim3(BB), dim3(THREADS), 0, stream,
                     x, adj, mask, W1, b1, W2, b2, Wc, bc, Wih, Whh, bih, bhh, P,
                     out_feat, out_adjm, out_assign);
}

// Round 2
// 458.178 us; speedup vs baseline: 1.8781x; 1.8781x over previous
//
#include <hip/hip_runtime.h>
#include <cfloat>
#include <cmath>

#define NB 2048      // nodes
#define BB 16        // batch
#define DD 128       // feature dim
#define HH 64        // hidden dim
#define MAXC 5
#define CSMAX 3
#define NSEL (MAXC * CSMAX)
#define THREADS 256

// ---------------- Threefry-2x32 (JAX-exact) ----------------
__device__ __forceinline__ unsigned rotl32(unsigned v, int d) {
  return (v << d) | (v >> (32 - d));
}

__device__ __forceinline__ void tf2x32(unsigned k0, unsigned k1, unsigned x0, unsigned x1,
                                       unsigned& o0, unsigned& o1) {
  unsigned ks2 = k0 ^ k1 ^ 0x1BD11BDAu;
  x0 += k0; x1 += k1;
#define RND(r) { x0 += x1; x1 = rotl32(x1, r); x1 ^= x0; }
  RND(13) RND(15) RND(26) RND(6)   x0 += k1;  x1 += ks2 + 1u;
  RND(17) RND(29) RND(16) RND(24)  x0 += ks2; x1 += k0 + 2u;
  RND(13) RND(15) RND(26) RND(6)   x0 += k0;  x1 += k1 + 3u;
  RND(17) RND(29) RND(16) RND(24)  x0 += k1;  x1 += ks2 + 4u;
  RND(13) RND(15) RND(26) RND(6)   x0 += ks2; x1 += k0 + 5u;
#undef RND
  o0 = x0; o1 = x1;
}

__device__ __forceinline__ float gumbel_for(unsigned k0, unsigned k1, unsigned idx) {
  unsigned o0, o1;
  tf2x32(k0, k1, 0u, idx, o0, o1);
  unsigned bits = o0 ^ o1;
  float u = __uint_as_float((bits >> 9) | 0x3f800000u) - 1.0f;
  float uu = u + 1e-8f;
  return -logf(-logf(uu) + 1e-8f);
}

// ---------------- Precompute P = x @ W1[:, :DD]^T  ([B*N, HH]) ----------------
__global__ __launch_bounds__(THREADS) void gvp_precompute(
    const float* __restrict__ x, const float* __restrict__ W1, float* __restrict__ P) {
  int gid = blockIdx.x * THREADS + threadIdx.x;  // B*N*HH total
  int j = gid & (HH - 1);
  int node = gid >> 6;
  if (node >= BB * NB) return;
  const float4* xr = (const float4*)(x + (size_t)node * DD);
  const float4* wr = (const float4*)(W1 + (size_t)j * (DD + HH));
  float acc = 0.f;
#pragma unroll
  for (int q = 0; q < DD / 4; q++) {
    float4 a = xr[q], w = wr[q];
    acc += a.x * w.x + a.y * w.y + a.z * w.z + a.w * w.w;
  }
  P[(size_t)node * HH + j] = acc;
}

// ---------------- Partial sums for per-batch node mean ----------------
// grid = BB*16 blocks; block (b, chunk) sums 128 nodes -> partial[b][chunk][d]
__global__ __launch_bounds__(THREADS) void gvp_mean_partial(
    const float* __restrict__ x, float* __restrict__ partial) {
  int b = blockIdx.x >> 4, chunk = blockIdx.x & 15;
  int d = threadIdx.x & (DD - 1), half = threadIdx.x >> 7;
  __shared__ float sp[2][DD];
  float acc = 0.f;
  int nend = chunk * 128 + 128;
  for (int n = chunk * 128 + half; n < nend; n += 2)
    acc += x[((size_t)b * NB + n) * DD + d];
  sp[half][d] = acc;
  __syncthreads();
  if (threadIdx.x < DD)
    partial[((size_t)b * 16 + chunk) * DD + threadIdx.x] = sp[0][threadIdx.x] + sp[1][threadIdx.x];
}

// ---------------- Precompute all Gumbel noise [NSEL][B][N] ----------------
__global__ __launch_bounds__(THREADS) void gvp_gumbel(float* __restrict__ gumb) {
  int gid = blockIdx.x * THREADS + threadIdx.x;
  if (gid >= NSEL * BB * NB) return;
  int sel = gid >> 15;            // / (BB*NB)
  int rem = gid & (BB * NB - 1);
  int c = sel / 3, s = sel - 3 * c;
  unsigned data = (s == 0) ? (unsigned)(2 * c) : (unsigned)(2 * c + 1000 + (s - 1));
  unsigned k0, k1;
  tf2x32(0u, 42u, 0u, data, k0, k1);  // fold_in(key(42), data)
  gumb[gid] = gumbel_for(k0, k1, (unsigned)rem);
}

// ---------------- Main sequential kernel: one block per batch ----------------
__global__ __launch_bounds__(THREADS) void gvp_main(
    const float* __restrict__ x, const float* __restrict__ adj,
    const int* __restrict__ mask,
    const float* __restrict__ W1, const float* __restrict__ b1,
    const float* __restrict__ W2, const float* __restrict__ b2,
    const float* __restrict__ Wc, const float* __restrict__ bc,
    const float* __restrict__ Wih, const float* __restrict__ Whh,
    const float* __restrict__ bih, const float* __restrict__ bhh,
    const float* __restrict__ P, const float* __restrict__ partial,
    const float* __restrict__ gumb,
    float* __restrict__ out_feat, float* __restrict__ out_adjm, float* __restrict__ out_assign) {
  const int b = blockIdx.x;
  const int tid = threadIdx.x;

  __shared__ __align__(16) float s_logits[NB];
  __shared__ unsigned char s_avail[NB], s_reach[NB], s_nb[NB], s_cur[NB];
  __shared__ short s_list[NB];
  __shared__ int s_cnt;
  __shared__ __align__(16) float s_ctx[HH], s_q[HH], s_h[HH];
  __shared__ __align__(16) float s_hist[MAXC][DD];
  __shared__ __align__(16) float s_giAll[MAXC][3 * HH];
  __shared__ __align__(16) float s_gh[3 * HH];
  __shared__ __align__(16) float s_Whh[3 * HH][HH];   // 48 KB
  __shared__ __align__(16) float s_W1c[HH][HH];       // 16 KB (W1[:, DD:])
  __shared__ __align__(16) float s_W2[HH];
  __shared__ float s_bih[3 * HH], s_bhh[3 * HH], s_b1[HH];
  __shared__ __align__(16) float s_mean[DD];
  __shared__ float s_redv[4];
  __shared__ int s_redi[4];
  __shared__ int s_mem[CSMAX];
  __shared__ int s_memCnt;
  __shared__ int s_selIdx;

  const size_t xb = (size_t)b * NB * DD;
  const size_t adjb = (size_t)b * NB * NB;

  // ---- stage weights into LDS (one-time) ----
  {
    const float4* src = (const float4*)Whh;
    float4* dst = (float4*)&s_Whh[0][0];
    for (int i = tid; i < 3 * HH * HH / 4; i += THREADS) dst[i] = src[i];
  }
  for (int i = tid; i < HH * HH / 4; i += THREADS) {
    int r = i >> 4, k4 = i & 15;
    *(float4*)&s_W1c[r][k4 * 4] = *(const float4*)(W1 + (size_t)r * (DD + HH) + DD + k4 * 4);
  }
  if (tid < HH) { s_W2[tid] = W2[tid]; s_b1[tid] = b1[tid]; }
  if (tid < 3 * HH) { s_bih[tid] = bih[tid]; s_bhh[tid] = bhh[tid]; }
  for (int n = tid; n < NB; n += THREADS) s_avail[n] = (mask[b * NB + n] != 0) ? 1 : 0;
  if (tid < DD) {
    float m = 0.f;
    for (int k = 0; k < 16; k++) m += partial[((size_t)b * 16 + k) * DD + tid];
    s_mean[tid] = m * (1.0f / NB);
  }
  if (tid == 0) s_memCnt = 0;
  __syncthreads();
  if (tid < HH) {
    float acc = bc[tid];
    const float4* wr = (const float4*)(Wc + (size_t)tid * DD);
    const float4* m4 = (const float4*)s_mean;
#pragma unroll
    for (int q = 0; q < DD / 4; q++) {
      float4 w = wr[q], m = m4[q];
      acc += w.x * m.x + w.y * m.y + w.z * m.z + w.w * m.w;
    }
    s_ctx[tid] = acc;
    s_h[tid] = 0.f;
  }
  __syncthreads();

  const float bias2 = b2[0];

  for (int c = 0; c < MAXC; c++) {
    // q = b1 + W1[:, DD:] @ ctx   (all from LDS)
    if (tid < HH) {
      float acc = s_b1[tid];
      const float4* wr = (const float4*)s_W1c[tid];
      const float4* c4 = (const float4*)s_ctx;
#pragma unroll
      for (int q = 0; q < HH / 4; q++) {
        float4 w = wr[q], cc = c4[q];
        acc += w.x * cc.x + w.y * cc.y + w.z * cc.z + w.w * cc.w;
      }
      s_q[tid] = acc;
    }
    if (tid == 0) s_memCnt = 0;
    __syncthreads();

    // logits[n] = b2 + sum_j W2[j] * relu(P[n,j] + q[j])
    for (int n = tid; n < NB; n += THREADS) {
      const float4* pr = (const float4*)(P + (size_t)(b * NB + n) * HH);
      const float4* q4 = (const float4*)s_q;
      const float4* w4 = (const float4*)s_W2;
      float acc = bias2;
#pragma unroll
      for (int q = 0; q < HH / 4; q++) {
        float4 p = pr[q], qq = q4[q], w = w4[q];
        float h0 = p.x + qq.x, h1 = p.y + qq.y, h2 = p.z + qq.z, h3 = p.w + qq.w;
        acc += w.x * (h0 > 0.f ? h0 : 0.f) + w.y * (h1 > 0.f ? h1 : 0.f) +
               w.z * (h2 > 0.f ? h2 : 0.f) + w.w * (h3 > 0.f ? h3 : 0.f);
      }
      s_logits[n] = acc;
    }
    __syncthreads();

    for (int s = 0; s < CSMAX; s++) {
      const float* gptr = gumb + ((size_t)(c * 3 + s) * BB + b) * NB;
      float bestv = -FLT_MAX;
      int besti = NB;
      for (int n = tid; n < NB; n += THREADS) {
        bool cand = s_avail[n] && (s == 0 || s_reach[n]);
        if (cand) {
          float y = s_logits[n] + gptr[n];
          if (y > bestv) { bestv = y; besti = n; }
        }
      }
      // wave-level argmax reduce (first-index tie-break)
#pragma unroll
      for (int off = 32; off > 0; off >>= 1) {
        float ov = __shfl_down(bestv, off);
        int oi = __shfl_down(besti, off);
        if (ov > bestv || (ov == bestv && oi < besti)) { bestv = ov; besti = oi; }
      }
      if ((tid & 63) == 0) { s_redv[tid >> 6] = bestv; s_redi[tid >> 6] = besti; }
      __syncthreads();
      if (tid == 0) {
        float bv = s_redv[0]; int bi = s_redi[0];
        for (int w = 1; w < 4; w++) {
          float v2 = s_redv[w]; int i2 = s_redi[w];
          if (v2 > bv || (v2 == bv && i2 < bi)) { bv = v2; bi = i2; }
        }
        int sidx = (bv > -FLT_MAX) ? bi : -1;
        s_selIdx = sidx;
        if (sidx >= 0) { s_avail[sidx] = 0; s_mem[s_memCnt++] = sidx; }
      }
      __syncthreads();
      int selIdx = s_selIdx;

      if (s == 0) {
        // k-hop BFS from seed
        for (int n = tid; n < NB; n += THREADS) {
          unsigned char v = (selIdx >= 0 && n == selIdx) ? 1 : 0;
          s_reach[n] = v; s_cur[n] = v;
        }
        __syncthreads();
        for (int hop = 0; hop < 2; hop++) {
          if (tid == 0) s_cnt = 0;
          for (int i = tid; i < NB / 4; i += THREADS) ((int*)s_nb)[i] = 0;
          __syncthreads();
          for (int n = tid; n < NB; n += THREADS)
            if (s_cur[n]) { int p = atomicAdd(&s_cnt, 1); s_list[p] = (short)n; }
          __syncthreads();
          int cnt = s_cnt;
          int total = cnt << 9;  // cnt * 512 float4s per row
          for (int w = tid; w < total; w += THREADS) {
            int li = w >> 9;
            int m4 = w & 511;
            int n = s_list[li];
            float4 a = *(const float4*)(adj + adjb + (size_t)n * NB + (m4 << 2));
            int m = m4 << 2;
            if (a.x > 0.f) s_nb[m] = 1;
            if (a.y > 0.f) s_nb[m + 1] = 1;
            if (a.z > 0.f) s_nb[m + 2] = 1;
            if (a.w > 0.f) s_nb[m + 3] = 1;
          }
          __syncthreads();
          for (int m = tid; m < NB; m += THREADS) {
            unsigned char nbv = s_nb[m];
            unsigned char nw = (nbv && !s_reach[m]) ? 1 : 0;
            if (nbv) s_reach[m] = 1;
            s_cur[m] = nw;
          }
          __syncthreads();
        }
      }
    }  // selections

    // assign[:, :, c]
    {
      int m0 = s_memCnt > 0 ? s_mem[0] : -1;
      int m1 = s_memCnt > 1 ? s_mem[1] : -1;
      int m2 = s_memCnt > 2 ? s_mem[2] : -1;
      for (int n = tid; n < NB; n += THREADS) {
        float v = (n == m0 || n == m1 || n == m2) ? 1.0f : 0.0f;
        out_assign[(size_t)(b * NB + n) * MAXC + c] = v;
      }
    }
    // embedding = mean of member rows
    if (tid < DD) {
      float acc = 0.f;
      int mc = s_memCnt;
      for (int i = 0; i < mc; i++) acc += x[xb + (size_t)s_mem[i] * DD + tid];
      float denom = (mc > 0) ? (float)mc : 1.0f;
      float e = acc / denom;
      s_hist[c][tid] = e;
      out_feat[((size_t)b * MAXC + c) * DD + tid] = e;
    }
    __syncthreads();

    // gi for this cluster's embedding (Wih @ hist[c] + bih) — once, reused in re-runs
    if (tid < 3 * HH) {
      float acc = s_bih[tid];
      const float4* wi = (const float4*)(Wih + (size_t)tid * DD);
      const float4* h4 = (const float4*)s_hist[c];
#pragma unroll
      for (int q = 0; q < DD / 4; q++) {
        float4 w = wi[q], hh = h4[q];
        acc += w.x * hh.x + w.y * hh.y + w.z * hh.z + w.w * hh.w;
      }
      s_giAll[c][tid] = acc;
    }
    __syncthreads();

    // GRU over full history 0..c, h0 = previous h (all LDS)
    for (int t = 0; t <= c; t++) {
      if (tid < 3 * HH) {
        float acc = s_bhh[tid];
        const float4* wh = (const float4*)s_Whh[tid];
        const float4* hh = (const float4*)s_h;
#pragma unroll
        for (int q = 0; q < HH / 4; q++) {
          float4 w = wh[q], h4v = hh[q];
          acc += w.x * h4v.x + w.y * h4v.y + w.z * h4v.z + w.w * h4v.w;
        }
        s_gh[tid] = acc;
      }
      __syncthreads();
      if (tid < HH) {
        float gi_r = s_giAll[t][tid], gi_z = s_giAll[t][HH + tid], gi_n = s_giAll[t][2 * HH + tid];
        float r = 1.f / (1.f + expf(-(gi_r + s_gh[tid])));
        float z = 1.f / (1.f + expf(-(gi_z + s_gh[HH + tid])));
        float nn = tanhf(gi_n + r * s_gh[2 * HH + tid]);
        s_h[tid] = (1.f - z) * nn + z * s_h[tid];
      }
      __syncthreads();
    }
    if (tid < HH) s_ctx[tid] = s_h[tid];
    __syncthreads();
  }  // clusters

  // cluster_adj = ones - eye
  for (int i = tid; i < MAXC * MAXC; i += THREADS)
    out_adjm[(size_t)b * MAXC * MAXC + i] = ((i / MAXC) == (i % MAXC)) ? 0.f : 1.f;
}

extern "C" void kernel_launch(void* const* d_in, const int* in_sizes, int n_in,
                              void* d_out, int out_size, void* d_ws, size_t ws_size,
                              hipStream_t stream) {
  const float* x   = (const float*)d_in[0];
  const float* adj = (const float*)d_in[1];
  const int*   mask= (const int*)d_in[2];
  const float* W1  = (const float*)d_in[3];
  const float* b1  = (const float*)d_in[4];
  const float* W2  = (const float*)d_in[5];
  const float* b2  = (const float*)d_in[6];
  const float* Wc  = (const float*)d_in[7];
  const float* bc  = (const float*)d_in[8];
  const float* Wih = (const float*)d_in[9];
  const float* Whh = (const float*)d_in[10];
  const float* bih = (const float*)d_in[11];
  const float* bhh = (const float*)d_in[12];

  float* ws = (float*)d_ws;
  float* P       = ws;                                   // [B*N*HH]  8 MB
  float* partial = P + (size_t)BB * NB * HH;             // [B][16][DD] 128 KB
  float* gumb    = partial + (size_t)BB * 16 * DD;       // [NSEL][B][N] ~2 MB

  float* out = (float*)d_out;
  float* out_feat = out;                                     // [B,5,D]
  float* out_adjm = out + (size_t)BB * MAXC * DD;            // [B,5,5]
  float* out_assign = out_adjm + (size_t)BB * MAXC * MAXC;   // [B,N,5]

  hipLaunchKernelGGL(gvp_precompute, dim3((BB * NB * HH) / THREADS), dim3(THREADS), 0, stream,
                     x, W1, P);
  hipLaunchKernelGGL(gvp_mean_partial, dim3(BB * 16), dim3(THREADS), 0, stream, x, partial);
  hipLaunchKernelGGL(gvp_gumbel, dim3((NSEL * BB * NB + THREADS - 1) / THREADS), dim3(THREADS),
                     0, stream, gumb);
  hipLaunchKernelGGL(gvp_main, dim3(BB), dim3(THREADS), 0, stream,
                     x, adj, mask, W1, b1, W2, b2, Wc, bc, Wih, Whh, bih, bhh, P, partial, gumb,
                     out_feat, out_adjm, out_assign);
}

// Round 3
// 198.644 us; speedup vs baseline: 4.3318x; 2.3065x over previous
//
#include <hip/hip_runtime.h>
#include <cfloat>
#include <cmath>

#define NB 2048
#define BB 16
#define DD 128
#define HH 64
#define MAXC 5
#define CSMAX 3
#define NT 1024

// ---------------- Threefry-2x32 (JAX-exact) ----------------
__device__ __forceinline__ unsigned rotl32(unsigned v, int d) {
  return (v << d) | (v >> (32 - d));
}

__device__ __forceinline__ void tf2x32(unsigned k0, unsigned k1, unsigned x0, unsigned x1,
                                       unsigned& o0, unsigned& o1) {
  unsigned ks2 = k0 ^ k1 ^ 0x1BD11BDAu;
  x0 += k0; x1 += k1;
#define RND(r) { x0 += x1; x1 = rotl32(x1, r); x1 ^= x0; }
  RND(13) RND(15) RND(26) RND(6)   x0 += k1;  x1 += ks2 + 1u;
  RND(17) RND(29) RND(16) RND(24)  x0 += ks2; x1 += k0 + 2u;
  RND(13) RND(15) RND(26) RND(6)   x0 += k0;  x1 += k1 + 3u;
  RND(17) RND(29) RND(16) RND(24)  x0 += k1;  x1 += ks2 + 4u;
  RND(13) RND(15) RND(26) RND(6)   x0 += ks2; x1 += k0 + 5u;
#undef RND
  o0 = x0; o1 = x1;
}

__device__ __forceinline__ float gumbel_for(unsigned k0, unsigned k1, unsigned idx) {
  unsigned o0, o1;
  tf2x32(k0, k1, 0u, idx, o0, o1);
  unsigned bits = o0 ^ o1;
  float u = __uint_as_float((bits >> 9) | 0x3f800000u) - 1.0f;
  float uu = u + 1e-8f;
  return -logf(-logf(uu) + 1e-8f);
}

// ---------------- Fused prep: P-GEMM tiles + mean partials + gumbel ----------------
// grid: [0,128)   -> P tiles (256 nodes each, W1 staged in LDS, 4n x 4j register tile)
//       [128,384) -> mean partial chunks (16 per batch)
//       [384,504) -> gumbel table
__global__ __launch_bounds__(NT) void gvp_prep(
    const float* __restrict__ x, const float* __restrict__ W1,
    float* __restrict__ P, float* __restrict__ partial, float* __restrict__ gumb) {
  __shared__ __align__(16) float s_W1[HH][DD + 4];
  __shared__ float sp[8][DD];
  const int bid = blockIdx.x, tid = threadIdx.x;

  if (bid < 128) {
    for (int i = tid; i < HH * (DD / 4); i += NT) {   // 2048 float4
      int r = i >> 5, q = i & 31;
      *(float4*)&s_W1[r][q * 4] = *(const float4*)(W1 + (size_t)r * (DD + HH) + q * 4);
    }
    __syncthreads();
    const int jg = tid & 15, ng = tid >> 4;
    const int j0 = jg * 4;
    const size_t n0 = (size_t)bid * 256 + ng * 4;
    const float4* x4 = (const float4*)x;
    float acc[4][4];
#pragma unroll
    for (int i = 0; i < 4; i++)
#pragma unroll
      for (int q = 0; q < 4; q++) acc[i][q] = 0.f;
    for (int kq = 0; kq < 32; kq++) {
      float4 xv[4], wv[4];
#pragma unroll
      for (int i = 0; i < 4; i++) xv[i] = x4[(n0 + i) * 32 + kq];
#pragma unroll
      for (int q = 0; q < 4; q++) wv[q] = *(const float4*)&s_W1[j0 + q][kq * 4];
#pragma unroll
      for (int i = 0; i < 4; i++)
#pragma unroll
        for (int q = 0; q < 4; q++)
          acc[i][q] += xv[i].x * wv[q].x + xv[i].y * wv[q].y +
                       xv[i].z * wv[q].z + xv[i].w * wv[q].w;
    }
#pragma unroll
    for (int i = 0; i < 4; i++)
#pragma unroll
      for (int q = 0; q < 4; q++)
        P[(n0 + i) * HH + j0 + q] = acc[i][q];
  } else if (bid < 384) {
    const int bm = bid - 128;
    const int b = bm >> 4, chunk = bm & 15;
    const int d = tid & (DD - 1), part = tid >> 7;  // 8 parts
    float acc = 0.f;
    const int base = chunk * 128 + part;
#pragma unroll
    for (int k = 0; k < 16; k++)
      acc += x[((size_t)b * NB + base + k * 8) * DD + d];
    sp[part][d] = acc;
    __syncthreads();
    if (tid < DD) {
      float m = 0.f;
#pragma unroll
      for (int p = 0; p < 8; p++) m += sp[p][tid];
      partial[((size_t)b * 16 + chunk) * DD + tid] = m;
    }
  } else {
    const int bg = bid - 384;
    const int base = (bg * NT + tid) * 4;
#pragma unroll
    for (int i = 0; i < 4; i++) {
      int idx = base + i;
      int sel = idx >> 15;           // / (BB*NB)
      int rem = idx & 32767;
      int c = sel / 3, s = sel - 3 * c;
      unsigned data = (s == 0) ? (unsigned)(2 * c) : (unsigned)(2 * c + 1000 + (s - 1));
      unsigned k0, k1;
      tf2x32(0u, 42u, 0u, data, k0, k1);
      gumb[idx] = gumbel_for(k0, k1, (unsigned)rem);
    }
  }
}

// ---------------- Main sequential kernel: one block (1024 thr) per batch ----------------
__global__ __launch_bounds__(NT) void gvp_main(
    const float* __restrict__ x, const float* __restrict__ adj, const int* __restrict__ mask,
    const float* __restrict__ W1, const float* __restrict__ b1,
    const float* __restrict__ W2, const float* __restrict__ b2,
    const float* __restrict__ Wc, const float* __restrict__ bc,
    const float* __restrict__ Wih, const float* __restrict__ Whh,
    const float* __restrict__ bih, const float* __restrict__ bhh,
    const float* __restrict__ P, const float* __restrict__ partial,
    const float* __restrict__ gumb,
    float* __restrict__ out_feat, float* __restrict__ out_adjm, float* __restrict__ out_assign) {
  const int b = blockIdx.x;
  const int tid = threadIdx.x;
  const int wid = tid >> 6;

  __shared__ __align__(16) float s_logits[NB];
  __shared__ __align__(16) float s_gumb[2][NB];
  __shared__ unsigned char s_avail[NB], s_reach[NB];
  __shared__ short s_list[128];
  __shared__ int s_cnt;
  __shared__ __align__(16) float s_ctx[HH], s_q[HH], s_h[HH];
  __shared__ __align__(16) float s_hist[MAXC][DD];
  __shared__ __align__(16) float s_giAll[MAXC][3 * HH];
  __shared__ float s_gh[3 * HH];
  __shared__ __align__(16) float s_Whh[3 * HH][HH + 4];   // padded: stride 68
  __shared__ __align__(16) float s_W1c[HH][HH + 4];       // padded
  __shared__ __align__(16) float s_W2[HH];
  __shared__ float s_bhh[3 * HH], s_b1[HH];
  __shared__ __align__(16) float s_mean[DD];
  __shared__ __align__(16) float s_emb[CSMAX][DD];
  __shared__ float s_redv[16];
  __shared__ int s_redi[16];
  __shared__ int s_mem[CSMAX];
  __shared__ int s_memCnt, s_selIdx;
  __shared__ float s_b2v;

  const size_t xb = (size_t)b * NB * DD;
  const float4* adj4 = (const float4*)(adj + (size_t)b * NB * NB);
  const float4* P4 = (const float4*)(P + (size_t)b * NB * HH);

  auto finalReduce = [&]() {
    if (tid < 16) {
      float bv = s_redv[tid];
      int bi = s_redi[tid];
#pragma unroll
      for (int off = 8; off; off >>= 1) {
        float ov = __shfl_down(bv, off);
        int oi = __shfl_down(bi, off);
        if (ov > bv || (ov == bv && oi < bi)) { bv = ov; bi = oi; }
      }
      if (tid == 0) {
        int sidx = (bv > -FLT_MAX) ? bi : -1;
        s_selIdx = sidx;
        s_cnt = 0;
        if (sidx >= 0) { s_avail[sidx] = 0; s_mem[s_memCnt++] = sidx; }
      }
    }
  };

  // ---- one-time staging ----
  for (int i = tid; i < 3 * HH * (HH / 4); i += NT) {   // 3072 float4
    int r = i >> 4, q = i & 15;
    *(float4*)&s_Whh[r][q * 4] = *(const float4*)(Whh + (size_t)r * HH + q * 4);
  }
  {
    int r = tid >> 4, q = tid & 15;                      // exactly 1024
    *(float4*)&s_W1c[r][q * 4] = *(const float4*)(W1 + (size_t)r * (DD + HH) + DD + q * 4);
  }
  if (tid < 3 * HH) s_bhh[tid] = bhh[tid];
  if (tid < HH) { s_W2[tid] = W2[tid]; s_b1[tid] = b1[tid]; s_h[tid] = 0.f; }
  if (tid == 0) { s_b2v = b2[0]; s_memCnt = 0; }
#pragma unroll
  for (int r = 0; r < 2; r++) {
    int n = tid + r * NT;
    s_avail[n] = (mask[b * NB + n] != 0) ? 1 : 0;
  }
  if (tid < DD) {
    float m = 0.f;
#pragma unroll
    for (int k = 0; k < 16; k++) m += partial[((size_t)b * 16 + k) * DD + tid];
    s_mean[tid] = m * (1.0f / NB);
  }
  __syncthreads();
  // ctx init = bc + Wc @ mean  (4-lane split over k)
  if (tid < 4 * HH) {
    int row = tid >> 2, g = tid & 3;
    const float4* wr = (const float4*)(Wc + (size_t)row * DD) + g * 8;
    const float4* m4 = (const float4*)s_mean + g * 8;
    float s = 0.f;
#pragma unroll
    for (int i = 0; i < 8; i++) {
      float4 w = wr[i], m = m4[i];
      s += w.x * m.x + w.y * m.y + w.z * m.z + w.w * m.w;
    }
    s += __shfl_xor(s, 1);
    s += __shfl_xor(s, 2);
    if (g == 0) s_ctx[row] = s + bc[row];
  }
  __syncthreads();

  for (int c = 0; c < MAXC; c++) {
    // ---- cluster top: issue gumbel loads (regs), q matvec ----
    const float* g0p = gumb + ((size_t)(c * 3) * BB + b) * NB;
    const float4* g12 = (const float4*)(gumb + ((size_t)(c * 3 + 1 + (tid >> 9)) * BB + b) * NB);
    float4 gst = g12[tid & 511];
    const int n0 = tid, n1 = tid + NT;
    float gs0 = g0p[n0], gs1 = g0p[n1];
    if (tid < 4 * HH) {   // q = b1 + W1[:,DD:] @ ctx
      int row = tid >> 2, g = tid & 3;
      const float4* wr = (const float4*)&s_W1c[row][0] + g * 4;
      const float4* c4 = (const float4*)s_ctx + g * 4;
      float s = 0.f;
#pragma unroll
      for (int i = 0; i < 4; i++) {
        float4 w = wr[i], cc = c4[i];
        s += w.x * cc.x + w.y * cc.y + w.z * cc.z + w.w * cc.w;
      }
      s += __shfl_xor(s, 1);
      s += __shfl_xor(s, 2);
      if (g == 0) s_q[row] = s + s_b1[row];
    }
    if (tid == 0) s_memCnt = 0;
    __syncthreads();  // A

    // ---- logits + fused sel0 scan ----
    {
      float l0 = s_b2v, l1 = s_b2v;
      const float4* p0 = P4 + (size_t)n0 * 16;
      const float4* p1 = P4 + (size_t)n1 * 16;
      const float4* q4 = (const float4*)s_q;
      const float4* w4 = (const float4*)s_W2;
#pragma unroll
      for (int q = 0; q < 16; q++) {
        float4 pa = p0[q], pb = p1[q], qq = q4[q], w = w4[q];
        l0 += w.x * fmaxf(pa.x + qq.x, 0.f) + w.y * fmaxf(pa.y + qq.y, 0.f) +
              w.z * fmaxf(pa.z + qq.z, 0.f) + w.w * fmaxf(pa.w + qq.w, 0.f);
        l1 += w.x * fmaxf(pb.x + qq.x, 0.f) + w.y * fmaxf(pb.y + qq.y, 0.f) +
              w.z * fmaxf(pb.z + qq.z, 0.f) + w.w * fmaxf(pb.w + qq.w, 0.f);
      }
      s_logits[n0] = l0;
      s_logits[n1] = l1;
      float bestv = -FLT_MAX;
      int besti = NB;
      if (s_avail[n0]) { float y = l0 + gs0; if (y > bestv) { bestv = y; besti = n0; } }
      if (s_avail[n1]) { float y = l1 + gs1; if (y > bestv) { bestv = y; besti = n1; } }
#pragma unroll
      for (int off = 32; off; off >>= 1) {
        float ov = __shfl_down(bestv, off);
        int oi = __shfl_down(besti, off);
        if (ov > bestv || (ov == bestv && oi < besti)) { bestv = ov; besti = oi; }
      }
      if ((tid & 63) == 0) { s_redv[wid] = bestv; s_redi[wid] = besti; }
      ((float4*)s_gumb)[tid] = gst;   // stage sel1/sel2 gumbel rows
    }
    __syncthreads();  // B
    finalReduce();
    __syncthreads();  // C
    const int seed = s_selIdx;

    // ---- BFS hop0: seed row -> reach + frontier compact ----
    if (tid < 512) {
      if (seed >= 0) {
        float4 a = adj4[(size_t)seed * 512 + tid];
        int m = tid << 2;
        unsigned f0 = a.x > 0.f, f1 = a.y > 0.f, f2 = a.z > 0.f, f3 = a.w > 0.f;
        unsigned r = f0 | (f1 << 8) | (f2 << 16) | (f3 << 24);
        if ((seed >> 2) == tid) r |= 1u << ((seed & 3) * 8);
        ((unsigned*)s_reach)[tid] = r;
        if (f0 && m != seed)     { int p = atomicAdd(&s_cnt, 1); if (p < 128) s_list[p] = (short)m; }
        if (f1 && m + 1 != seed) { int p = atomicAdd(&s_cnt, 1); if (p < 128) s_list[p] = (short)(m + 1); }
        if (f2 && m + 2 != seed) { int p = atomicAdd(&s_cnt, 1); if (p < 128) s_list[p] = (short)(m + 2); }
        if (f3 && m + 3 != seed) { int p = atomicAdd(&s_cnt, 1); if (p < 128) s_list[p] = (short)(m + 3); }
      } else {
        ((unsigned*)s_reach)[tid] = 0u;
      }
    }
    __syncthreads();  // D

    // ---- BFS hop1: OR frontier rows into reach (independent guarded loads) ----
    if (seed >= 0) {
      int cnt = min(s_cnt, 128);
      int m4 = tid & 511, rg = tid >> 9;
      bool a0 = false, a1 = false, a2 = false, a3 = false;
#pragma unroll
      for (int k = 0; k < 20; k++) {
        int li = rg + 2 * k;
        if (li < cnt) {
          int n = s_list[li];
          float4 a = adj4[(size_t)n * 512 + m4];
          a0 |= a.x > 0.f; a1 |= a.y > 0.f; a2 |= a.z > 0.f; a3 |= a.w > 0.f;
        }
      }
      for (int li = rg + 40; li < cnt; li += 2) {   // safety tail (degree > 40)
        int n = s_list[li];
        float4 a = adj4[(size_t)n * 512 + m4];
        a0 |= a.x > 0.f; a1 |= a.y > 0.f; a2 |= a.z > 0.f; a3 |= a.w > 0.f;
      }
      int m = m4 << 2;
      if (a0) s_reach[m] = 1;
      if (a1) s_reach[m + 1] = 1;
      if (a2) s_reach[m + 2] = 1;
      if (a3) s_reach[m + 3] = 1;
    }
    __syncthreads();  // E

    // ---- sel1, sel2 (all LDS) ----
    for (int s = 1; s < CSMAX; s++) {
      float bv = -FLT_MAX;
      int bi = NB;
#pragma unroll
      for (int r = 0; r < 2; r++) {
        int n = tid + r * NT;
        if (s_avail[n] && s_reach[n]) {
          float y = s_logits[n] + s_gumb[s - 1][n];
          if (y > bv) { bv = y; bi = n; }
        }
      }
#pragma unroll
      for (int off = 32; off; off >>= 1) {
        float ov = __shfl_down(bv, off);
        int oi = __shfl_down(bi, off);
        if (ov > bv || (ov == bv && oi < bi)) { bv = ov; bi = oi; }
      }
      if ((tid & 63) == 0) { s_redv[wid] = bv; s_redi[wid] = bi; }
      __syncthreads();
      finalReduce();
      __syncthreads();
    }

    // ---- assign write + member-row loads ----
    {
      int mc = s_memCnt;
      int mm0 = mc > 0 ? s_mem[0] : -1;
      int mm1 = mc > 1 ? s_mem[1] : -1;
      int mm2 = mc > 2 ? s_mem[2] : -1;
#pragma unroll
      for (int r = 0; r < 2; r++) {
        int n = tid + r * NT;
        out_assign[(size_t)(b * NB + n) * MAXC + c] =
            (n == mm0 || n == mm1 || n == mm2) ? 1.0f : 0.0f;
      }
      if (tid < 384) {
        int rr = tid >> 7, d = tid & (DD - 1);
        if (rr < mc) s_emb[rr][d] = x[xb + (size_t)s_mem[rr] * DD + d];
      }
    }
    __syncthreads();  // J
    if (tid < DD) {
      int mc = s_memCnt;
      float acc = 0.f;
      if (mc > 0) acc += s_emb[0][tid];
      if (mc > 1) acc += s_emb[1][tid];
      if (mc > 2) acc += s_emb[2][tid];
      float e = acc / fmaxf((float)mc, 1.0f);
      s_hist[c][tid] = e;
      out_feat[((size_t)b * MAXC + c) * DD + tid] = e;
    }
    __syncthreads();  // K

    // ---- gi = bih + Wih @ hist[c]  (once per cluster; 4-lane split) ----
    if (tid < 4 * 3 * HH) {
      int row = tid >> 2, g = tid & 3;
      const float4* wr = (const float4*)(Wih + (size_t)row * DD) + g * 8;
      const float4* h4 = (const float4*)s_hist[c] + g * 8;
      float s = 0.f;
#pragma unroll
      for (int i = 0; i < 8; i++) {
        float4 w = wr[i], hh = h4[i];
        s += w.x * hh.x + w.y * hh.y + w.z * hh.z + w.w * hh.w;
      }
      s += __shfl_xor(s, 1);
      s += __shfl_xor(s, 2);
      if (g == 0) s_giAll[c][row] = s + bih[row];
    }
    __syncthreads();  // L

    // ---- GRU over history 0..c, h0 = previous h ----
    for (int t0 = 0; t0 <= c; t0++) {
      if (tid < 4 * 3 * HH) {
        int row = tid >> 2, g = tid & 3;
        const float4* wr = (const float4*)&s_Whh[row][0] + g * 4;
        const float4* h4 = (const float4*)s_h + g * 4;
        float s = 0.f;
#pragma unroll
        for (int i = 0; i < 4; i++) {
          float4 w = wr[i], hh = h4[i];
          s += w.x * hh.x + w.y * hh.y + w.z * hh.z + w.w * hh.w;
        }
        s += __shfl_xor(s, 1);
        s += __shfl_xor(s, 2);
        if (g == 0) s_gh[row] = s + s_bhh[row];
      }
      __syncthreads();
      if (tid < HH) {
        float r = 1.f / (1.f + expf(-(s_giAll[t0][tid] + s_gh[tid])));
        float z = 1.f / (1.f + expf(-(s_giAll[t0][HH + tid] + s_gh[HH + tid])));
        float nn = tanhf(s_giAll[t0][2 * HH + tid] + r * s_gh[2 * HH + tid]);
        float hn = (1.f - z) * nn + z * s_h[tid];
        s_h[tid] = hn;
        if (t0 == c) s_ctx[tid] = hn;
      }
      __syncthreads();
    }
  }  // clusters

  for (int i = tid; i < MAXC * MAXC; i += NT)
    out_adjm[(size_t)b * MAXC * MAXC + i] = ((i / MAXC) == (i % MAXC)) ? 0.f : 1.f;
}

extern "C" void kernel_launch(void* const* d_in, const int* in_sizes, int n_in,
                              void* d_out, int out_size, void* d_ws, size_t ws_size,
                              hipStream_t stream) {
  const float* x   = (const float*)d_in[0];
  const float* adj = (const float*)d_in[1];
  const int*   mask= (const int*)d_in[2];
  const float* W1  = (const float*)d_in[3];
  const float* b1  = (const float*)d_in[4];
  const float* W2  = (const float*)d_in[5];
  const float* b2  = (const float*)d_in[6];
  const float* Wc  = (const float*)d_in[7];
  const float* bc  = (const float*)d_in[8];
  const float* Wih = (const float*)d_in[9];
  const float* Whh = (const float*)d_in[10];
  const float* bih = (const float*)d_in[11];
  const float* bhh = (const float*)d_in[12];

  float* ws = (float*)d_ws;
  float* P       = ws;                                   // [B*N*HH]  8 MB
  float* partial = P + (size_t)BB * NB * HH;             // [B][16][DD]
  float* gumb    = partial + (size_t)BB * 16 * DD;       // [15][B][N]

  float* out = (float*)d_out;
  float* out_feat = out;                                     // [B,5,D]
  float* out_adjm = out + (size_t)BB * MAXC * DD;            // [B,5,5]
  float* out_assign = out_adjm + (size_t)BB * MAXC * MAXC;   // [B,N,5]

  hipLaunchKernelGGL(gvp_prep, dim3(504), dim3(NT), 0, stream, x, W1, P, partial, gumb);
  hipLaunchKernelGGL(gvp_main, dim3(BB), dim3(NT), 0, stream,
                     x, adj, mask, W1, b1, W2, b2, Wc, bc, Wih, Whh, bih, bhh, P, partial, gumb,
                     out_feat, out_adjm, out_assign);
}

// Round 4
// 194.965 us; speedup vs baseline: 4.4136x; 1.0189x over previous
//
#include <hip/hip_runtime.h>
#include <cfloat>
#include <cmath>

#define NB 2048
#define BB 16
#define DD 128
#define HH 64
#define MAXC 5
#define CSMAX 3
#define NT 1024

// ---------------- Threefry-2x32 (JAX-exact) ----------------
__device__ __forceinline__ unsigned rotl32(unsigned v, int d) {
  return (v << d) | (v >> (32 - d));
}

__device__ __forceinline__ void tf2x32(unsigned k0, unsigned k1, unsigned x0, unsigned x1,
                                       unsigned& o0, unsigned& o1) {
  unsigned ks2 = k0 ^ k1 ^ 0x1BD11BDAu;
  x0 += k0; x1 += k1;
#define RND(r) { x0 += x1; x1 = rotl32(x1, r); x1 ^= x0; }
  RND(13) RND(15) RND(26) RND(6)   x0 += k1;  x1 += ks2 + 1u;
  RND(17) RND(29) RND(16) RND(24)  x0 += ks2; x1 += k0 + 2u;
  RND(13) RND(15) RND(26) RND(6)   x0 += k0;  x1 += k1 + 3u;
  RND(17) RND(29) RND(16) RND(24)  x0 += k1;  x1 += ks2 + 4u;
  RND(13) RND(15) RND(26) RND(6)   x0 += ks2; x1 += k0 + 5u;
#undef RND
  o0 = x0; o1 = x1;
}

__device__ __forceinline__ float gumbel_for(unsigned k0, unsigned k1, unsigned idx) {
  unsigned o0, o1;
  tf2x32(k0, k1, 0u, idx, o0, o1);
  unsigned bits = o0 ^ o1;
  float u = __uint_as_float((bits >> 9) | 0x3f800000u) - 1.0f;
  float uu = u + 1e-8f;
  return -logf(-logf(uu) + 1e-8f);
}

// ---------------- Fused prep: P-GEMM tiles + mean partials + gumbel ----------------
__global__ __launch_bounds__(NT) void gvp_prep(
    const float* __restrict__ x, const float* __restrict__ W1,
    float* __restrict__ P, float* __restrict__ partial, float* __restrict__ gumb) {
  __shared__ __align__(16) float s_W1[HH][DD + 4];
  __shared__ float sp[8][DD];
  const int bid = blockIdx.x, tid = threadIdx.x;

  if (bid < 128) {
    for (int i = tid; i < HH * (DD / 4); i += NT) {
      int r = i >> 5, q = i & 31;
      *(float4*)&s_W1[r][q * 4] = *(const float4*)(W1 + (size_t)r * (DD + HH) + q * 4);
    }
    __syncthreads();
    const int jg = tid & 15, ng = tid >> 4;
    const int j0 = jg * 4;
    const size_t n0 = (size_t)bid * 256 + ng * 4;
    const float4* x4 = (const float4*)x;
    float acc[4][4];
#pragma unroll
    for (int i = 0; i < 4; i++)
#pragma unroll
      for (int q = 0; q < 4; q++) acc[i][q] = 0.f;
    for (int kq = 0; kq < 32; kq++) {
      float4 xv[4], wv[4];
#pragma unroll
      for (int i = 0; i < 4; i++) xv[i] = x4[(n0 + i) * 32 + kq];
#pragma unroll
      for (int q = 0; q < 4; q++) wv[q] = *(const float4*)&s_W1[j0 + q][kq * 4];
#pragma unroll
      for (int i = 0; i < 4; i++)
#pragma unroll
        for (int q = 0; q < 4; q++)
          acc[i][q] += xv[i].x * wv[q].x + xv[i].y * wv[q].y +
                       xv[i].z * wv[q].z + xv[i].w * wv[q].w;
    }
#pragma unroll
    for (int i = 0; i < 4; i++)
#pragma unroll
      for (int q = 0; q < 4; q++)
        P[(n0 + i) * HH + j0 + q] = acc[i][q];
  } else if (bid < 384) {
    const int bm = bid - 128;
    const int b = bm >> 4, chunk = bm & 15;
    const int d = tid & (DD - 1), part = tid >> 7;
    float acc = 0.f;
    const int base = chunk * 128 + part;
#pragma unroll
    for (int k = 0; k < 16; k++)
      acc += x[((size_t)b * NB + base + k * 8) * DD + d];
    sp[part][d] = acc;
    __syncthreads();
    if (tid < DD) {
      float m = 0.f;
#pragma unroll
      for (int p = 0; p < 8; p++) m += sp[p][tid];
      partial[((size_t)b * 16 + chunk) * DD + tid] = m;
    }
  } else {
    const int bg = bid - 384;
    const int base = (bg * NT + tid) * 4;
#pragma unroll
    for (int i = 0; i < 4; i++) {
      int idx = base + i;
      int sel = idx >> 15;
      int rem = idx & 32767;
      int c = sel / 3, s = sel - 3 * c;
      unsigned data = (s == 0) ? (unsigned)(2 * c) : (unsigned)(2 * c + 1000 + (s - 1));
      unsigned k0, k1;
      tf2x32(0u, 42u, 0u, data, k0, k1);
      gumb[idx] = gumbel_for(k0, k1, (unsigned)rem);
    }
  }
}

// ---------------- Main: one block (1024 thr, 128 VGPR) per batch ----------------
__global__ __launch_bounds__(NT, 4) void gvp_main(
    const float* __restrict__ x, const float* __restrict__ adj, const int* __restrict__ mask,
    const float* __restrict__ W1, const float* __restrict__ b1,
    const float* __restrict__ W2, const float* __restrict__ b2,
    const float* __restrict__ Wc, const float* __restrict__ bc,
    const float* __restrict__ Wih, const float* __restrict__ Whh,
    const float* __restrict__ bih, const float* __restrict__ bhh,
    const float* __restrict__ P, const float* __restrict__ partial,
    const float* __restrict__ gumb,
    float* __restrict__ out_feat, float* __restrict__ out_adjm, float* __restrict__ out_assign) {
  const int b = blockIdx.x;
  const int tid = threadIdx.x;

  __shared__ __align__(16) float s_logits[NB];
  __shared__ __align__(16) float s_gumb[2][NB];
  __shared__ unsigned char s_avail[NB], s_reach[NB], s_assignB[NB];
  __shared__ short s_list[128];
  __shared__ int s_cnt;
  __shared__ unsigned long long s_key[CSMAX];
  __shared__ __align__(16) float s_ctx[HH], s_q[HH];
  __shared__ __align__(16) float s_h[2][HH];
  __shared__ __align__(16) float s_hist[MAXC][DD];
  __shared__ __align__(16) float s_giAll[MAXC][3 * HH];
  __shared__ __align__(16) float s_Whh[3 * HH][HH + 4];
  __shared__ __align__(16) float s_W1c[HH][HH + 4];
  __shared__ __align__(16) float s_W2[HH];
  __shared__ float s_bhh[3 * HH], s_b1[HH];
  __shared__ __align__(16) float s_mean[DD];
  __shared__ float s_b2v;

  const size_t xb = (size_t)b * NB * DD;
  const float4* adj4 = (const float4*)(adj + (size_t)b * NB * NB);
  const float4* P4 = (const float4*)(P + (size_t)b * NB * HH);

  // scan-reduce: wave shfl argmax -> one packed u64 atomicMax per wave
  auto scanReduce = [&](float bv, int bi, int slot) {
#pragma unroll
    for (int off = 32; off; off >>= 1) {
      float ov = __shfl_down(bv, off);
      int oi = __shfl_down(bi, off);
      if (ov > bv || (ov == bv && oi < bi)) { bv = ov; bi = oi; }
    }
    if ((tid & 63) == 0 && bi < NB) {
      unsigned u = __float_as_uint(bv);
      u = (u & 0x80000000u) ? ~u : (u | 0x80000000u);
      unsigned long long key = ((unsigned long long)u << 32) | (unsigned)(~bi);
      atomicMax(&s_key[slot], key);
    }
  };
  auto decodeIdx = [](unsigned long long k) -> int {
    return k ? (int)(unsigned)(~(unsigned)k) : -1;
  };

  // ---- one-time staging ----
  for (int i = tid; i < 3 * HH * (HH / 4); i += NT) {
    int r = i >> 4, q = i & 15;
    *(float4*)&s_Whh[r][q * 4] = *(const float4*)(Whh + (size_t)r * HH + q * 4);
  }
  {
    int r = tid >> 4, q = tid & 15;
    *(float4*)&s_W1c[r][q * 4] = *(const float4*)(W1 + (size_t)r * (DD + HH) + DD + q * 4);
  }
  if (tid < 3 * HH) s_bhh[tid] = bhh[tid];
  if (tid < HH) { s_W2[tid] = W2[tid]; s_b1[tid] = b1[tid]; s_h[0][tid] = 0.f; }
  if (tid == 0) s_b2v = b2[0];
#pragma unroll
  for (int r = 0; r < 2; r++) {
    int n = tid + r * NT;
    s_avail[n] = (mask[b * NB + n] != 0) ? 1 : 0;
    s_assignB[n] = 0;
  }
  if (tid < DD) {
    float m = 0.f;
#pragma unroll
    for (int k = 0; k < 16; k++) m += partial[((size_t)b * 16 + k) * DD + tid];
    s_mean[tid] = m * (1.0f / NB);
  }
  __syncthreads();
  if (tid < 4 * HH) {  // ctx = bc + Wc @ mean
    int row = tid >> 2, g = tid & 3;
    const float4* wr = (const float4*)(Wc + (size_t)row * DD) + g * 8;
    const float4* m4 = (const float4*)s_mean + g * 8;
    float s = 0.f;
#pragma unroll
    for (int i = 0; i < 8; i++) {
      float4 w = wr[i], m = m4[i];
      s += w.x * m.x + w.y * m.y + w.z * m.z + w.w * m.w;
    }
    s += __shfl_xor(s, 1);
    s += __shfl_xor(s, 2);
    if (g == 0) s_ctx[row] = s + bc[row];
  }
  __syncthreads();

  int hp = 0;  // GRU h parity (uniform across threads)

  for (int c = 0; c < MAXC; c++) {
    // ======== TOP: gumbel stage + q matvec + state reset ========
    const float* g0p = gumb + ((size_t)(c * 3) * BB + b) * NB;
    const float4* g12 = (const float4*)(gumb + ((size_t)(c * 3 + 1 + (tid >> 9)) * BB + b) * NB);
    float4 gst = g12[tid & 511];
    const int n0 = tid, n1 = tid + NT;
    float gs0 = g0p[n0], gs1 = g0p[n1];
    ((float4*)s_gumb)[tid] = gst;
    if (tid < 4 * HH) {  // q = b1 + W1[:,DD:] @ ctx
      int row = tid >> 2, g = tid & 3;
      const float4* wr = (const float4*)&s_W1c[row][0] + g * 4;
      const float4* c4 = (const float4*)s_ctx + g * 4;
      float s = 0.f;
#pragma unroll
      for (int i = 0; i < 4; i++) {
        float4 w = wr[i], cc = c4[i];
        s += w.x * cc.x + w.y * cc.y + w.z * cc.z + w.w * cc.w;
      }
      s += __shfl_xor(s, 1);
      s += __shfl_xor(s, 2);
      if (g == 0) s_q[row] = s + s_b1[row];
    }
    if (tid < CSMAX) s_key[tid] = 0ull;
    if (tid == 0) s_cnt = 0;
    __syncthreads();

    // ======== LOGITS + SEL0 scan ========
    {
      float l0 = s_b2v, l1 = s_b2v;
      const float4* p0 = P4 + (size_t)n0 * 16;
      const float4* p1 = P4 + (size_t)n1 * 16;
      const float4* q4 = (const float4*)s_q;
      const float4* w4 = (const float4*)s_W2;
#pragma unroll
      for (int qq = 0; qq < 16; qq += 4) {
        float4 A[4], Bv[4];
#pragma unroll
        for (int i = 0; i < 4; i++) { A[i] = p0[qq + i]; Bv[i] = p1[qq + i]; }
#pragma unroll
        for (int i = 0; i < 4; i++) {
          float4 qv = q4[qq + i], w = w4[qq + i];
          l0 += w.x * fmaxf(A[i].x + qv.x, 0.f) + w.y * fmaxf(A[i].y + qv.y, 0.f) +
                w.z * fmaxf(A[i].z + qv.z, 0.f) + w.w * fmaxf(A[i].w + qv.w, 0.f);
          l1 += w.x * fmaxf(Bv[i].x + qv.x, 0.f) + w.y * fmaxf(Bv[i].y + qv.y, 0.f) +
                w.z * fmaxf(Bv[i].z + qv.z, 0.f) + w.w * fmaxf(Bv[i].w + qv.w, 0.f);
        }
      }
      s_logits[n0] = l0;
      s_logits[n1] = l1;
      float bv = -FLT_MAX;
      int bi = NB;
      if (s_avail[n0]) { float y = l0 + gs0; if (y > bv) { bv = y; bi = n0; } }
      if (s_avail[n1]) { float y = l1 + gs1; if (y > bv || (y == bv && n1 < bi)) { bv = y; bi = n1; } }
      scanReduce(bv, bi, 0);
    }
    __syncthreads();

    // ======== HOP0: seed row -> reach + frontier ========
    const int seed = decodeIdx(s_key[0]);
    if (tid < 512) {
      if (seed >= 0) {
        float4 a = adj4[(size_t)seed * 512 + tid];
        int m = tid << 2;
        unsigned f0 = a.x > 0.f, f1 = a.y > 0.f, f2 = a.z > 0.f, f3 = a.w > 0.f;
        unsigned r = f0 | (f1 << 8) | (f2 << 16) | (f3 << 24);
        if ((seed >> 2) == tid) r |= 1u << ((seed & 3) * 8);
        ((unsigned*)s_reach)[tid] = r;
        if (f0 && m != seed)     { int p = atomicAdd(&s_cnt, 1); if (p < 128) s_list[p] = (short)m; }
        if (f1 && m + 1 != seed) { int p = atomicAdd(&s_cnt, 1); if (p < 128) s_list[p] = (short)(m + 1); }
        if (f2 && m + 2 != seed) { int p = atomicAdd(&s_cnt, 1); if (p < 128) s_list[p] = (short)(m + 2); }
        if (f3 && m + 3 != seed) { int p = atomicAdd(&s_cnt, 1); if (p < 128) s_list[p] = (short)(m + 3); }
      } else {
        ((unsigned*)s_reach)[tid] = 0u;
      }
    }
    __syncthreads();

    // ======== HOP1: OR frontier rows into reach ========
    if (seed >= 0) {
      int cnt = min(s_cnt, 128);
      int m4 = tid & 511, rg = tid >> 9;
      bool a0 = false, a1 = false, a2 = false, a3 = false;
#pragma unroll
      for (int k = 0; k < 20; k++) {
        int li = rg + 2 * k;
        if (li < cnt) {
          int n = s_list[li];
          float4 a = adj4[(size_t)n * 512 + m4];
          a0 |= a.x > 0.f; a1 |= a.y > 0.f; a2 |= a.z > 0.f; a3 |= a.w > 0.f;
        }
      }
      for (int li = rg + 40; li < cnt; li += 2) {
        int n = s_list[li];
        float4 a = adj4[(size_t)n * 512 + m4];
        a0 |= a.x > 0.f; a1 |= a.y > 0.f; a2 |= a.z > 0.f; a3 |= a.w > 0.f;
      }
      int m = m4 << 2;
      if (a0) s_reach[m] = 1;
      if (a1) s_reach[m + 1] = 1;
      if (a2) s_reach[m + 2] = 1;
      if (a3) s_reach[m + 3] = 1;
    }
    __syncthreads();

    // ======== SEL1 ========
    {
      float bv = -FLT_MAX;
      int bi = NB;
#pragma unroll
      for (int r = 0; r < 2; r++) {
        int n = tid + r * NT;
        if (s_avail[n] && s_reach[n] && n != seed) {
          float y = s_logits[n] + s_gumb[0][n];
          if (y > bv || (y == bv && n < bi)) { bv = y; bi = n; }
        }
      }
      scanReduce(bv, bi, 1);
    }
    __syncthreads();

    // ======== SEL2 ========
    const int w1i = decodeIdx(s_key[1]);
    {
      float bv = -FLT_MAX;
      int bi = NB;
#pragma unroll
      for (int r = 0; r < 2; r++) {
        int n = tid + r * NT;
        if (s_avail[n] && s_reach[n] && n != seed && n != w1i) {
          float y = s_logits[n] + s_gumb[1][n];
          if (y > bv || (y == bv && n < bi)) { bv = y; bi = n; }
        }
      }
      scanReduce(bv, bi, 2);
    }
    __syncthreads();

    // ======== EMB + avail/assign update ========
    const int w2i = decodeIdx(s_key[2]);
    {
      int mc = (seed >= 0) + (w1i >= 0) + (w2i >= 0);
      if (tid < DD) {
        float acc = 0.f;
        if (seed >= 0) acc += x[xb + (size_t)seed * DD + tid];
        if (w1i >= 0) acc += x[xb + (size_t)w1i * DD + tid];
        if (w2i >= 0) acc += x[xb + (size_t)w2i * DD + tid];
        float e = acc / fmaxf((float)mc, 1.0f);
        s_hist[c][tid] = e;
        out_feat[((size_t)b * MAXC + c) * DD + tid] = e;
      } else if (tid >= 128 && tid < 128 + CSMAX) {
        int idx = (tid == 128) ? seed : (tid == 129 ? w1i : w2i);
        if (idx >= 0) { s_avail[idx] = 0; s_assignB[idx] |= (unsigned char)(1 << c); }
      }
    }
    __syncthreads();

    // ======== GI: bih + Wih @ hist[c] ========
    if (tid < 4 * 3 * HH) {
      int row = tid >> 2, g = tid & 3;
      const float4* wr = (const float4*)(Wih + (size_t)row * DD) + g * 8;
      const float4* h4 = (const float4*)s_hist[c] + g * 8;
      float s = 0.f;
#pragma unroll
      for (int i = 0; i < 8; i++) {
        float4 w = wr[i], hh = h4[i];
        s += w.x * hh.x + w.y * hh.y + w.z * hh.z + w.w * hh.w;
      }
      s += __shfl_xor(s, 1);
      s += __shfl_xor(s, 2);
      if (g == 0) s_giAll[c][row] = s + bih[row];
    }
    __syncthreads();

    // ======== GRU over history 0..c (1 barrier/step, double-buffered h) ========
    for (int t0 = 0; t0 <= c; t0++) {
      if (tid < 4 * HH) {
        int row = tid >> 2, g = tid & 3;
        const float4* h4 = (const float4*)s_h[hp] + g * 4;
        float4 hv[4];
#pragma unroll
        for (int i = 0; i < 4; i++) hv[i] = h4[i];
        const float4* wr = (const float4*)&s_Whh[row][0] + g * 4;
        const float4* wz = (const float4*)&s_Whh[HH + row][0] + g * 4;
        const float4* wn = (const float4*)&s_Whh[2 * HH + row][0] + g * 4;
        float sr = 0.f, sz = 0.f, sn = 0.f;
#pragma unroll
        for (int i = 0; i < 4; i++) {
          float4 a = wr[i], bz = wz[i], cn = wn[i], h = hv[i];
          sr += a.x * h.x + a.y * h.y + a.z * h.z + a.w * h.w;
          sz += bz.x * h.x + bz.y * h.y + bz.z * h.z + bz.w * h.w;
          sn += cn.x * h.x + cn.y * h.y + cn.z * h.z + cn.w * h.w;
        }
        sr += __shfl_xor(sr, 1); sr += __shfl_xor(sr, 2);
        sz += __shfl_xor(sz, 1); sz += __shfl_xor(sz, 2);
        sn += __shfl_xor(sn, 1); sn += __shfl_xor(sn, 2);
        if (g == 0) {
          float r = 1.f / (1.f + expf(-(s_giAll[t0][row] + sr + s_bhh[row])));
          float z = 1.f / (1.f + expf(-(s_giAll[t0][HH + row] + sz + s_bhh[HH + row])));
          float nn = tanhf(s_giAll[t0][2 * HH + row] + r * (sn + s_bhh[2 * HH + row]));
          float hn = (1.f - z) * nn + z * s_h[hp][row];
          s_h[hp ^ 1][row] = hn;
          if (t0 == c) s_ctx[row] = hn;
        }
      }
      hp ^= 1;
      __syncthreads();
    }
  }  // clusters

  // ======== final coalesced assign + cluster_adj writes ========
#pragma unroll
  for (int r = 0; r < 2; r++) {
    int n = tid + r * NT;
    unsigned bits = s_assignB[n];
    size_t base = ((size_t)(b * NB + n)) * MAXC;
#pragma unroll
    for (int cc = 0; cc < MAXC; cc++)
      out_assign[base + cc] = (float)((bits >> cc) & 1u);
  }
  for (int i = tid; i < MAXC * MAXC; i += NT)
    out_adjm[(size_t)b * MAXC * MAXC + i] = ((i / MAXC) == (i % MAXC)) ? 0.f : 1.f;
}

extern "C" void kernel_launch(void* const* d_in, const int* in_sizes, int n_in,
                              void* d_out, int out_size, void* d_ws, size_t ws_size,
                              hipStream_t stream) {
  const float* x   = (const float*)d_in[0];
  const float* adj = (const float*)d_in[1];
  const int*   mask= (const int*)d_in[2];
  const float* W1  = (const float*)d_in[3];
  const float* b1  = (const float*)d_in[4];
  const float* W2  = (const float*)d_in[5];
  const float* b2  = (const float*)d_in[6];
  const float* Wc  = (const float*)d_in[7];
  const float* bc  = (const float*)d_in[8];
  const float* Wih = (const float*)d_in[9];
  const float* Whh = (const float*)d_in[10];
  const float* bih = (const float*)d_in[11];
  const float* bhh = (const float*)d_in[12];

  float* ws = (float*)d_ws;
  float* P       = ws;                                   // [B*N*HH]  8 MB
  float* partial = P + (size_t)BB * NB * HH;             // [B][16][DD]
  float* gumb    = partial + (size_t)BB * 16 * DD;       // [15][B][N]

  float* out = (float*)d_out;
  float* out_feat = out;                                     // [B,5,D]
  float* out_adjm = out + (size_t)BB * MAXC * DD;            // [B,5,5]
  float* out_assign = out_adjm + (size_t)BB * MAXC * MAXC;   // [B,N,5]

  hipLaunchKernelGGL(gvp_prep, dim3(504), dim3(NT), 0, stream, x, W1, P, partial, gumb);
  hipLaunchKernelGGL(gvp_main, dim3(BB), dim3(NT), 0, stream,
                     x, adj, mask, W1, b1, W2, b2, Wc, bc, Wih, Whh, bih, bhh, P, partial, gumb,
                     out_feat, out_adjm, out_assign);
}